// Round 8
// baseline (208.023 us; speedup 1.0000x reference)
//
#include <hip/hip_runtime.h>
#include <hip/hip_bf16.h>

// EdgeDecoder: out[e] = w2 . relu(W1 @ concat(z_sotu[row[e]], z_taxon[col[e]]) + b1) + b2
// E=1e6, H=128, K=2H=256. fp32 inputs, int32 indices, fp32 output.
//
// Round 8 (U/V decomposition, bookkeeping corrected: bench has ~80us fixed
// harness overhead; optimizable = prep ~57us + edge ~67us):
//  - w1cvt: one-shot W1 fp32->bf16 (32K elems, ~2us).
//  - prep v3: U = zs@W1s^T + b1, V = zt@W1t^T. R6/R7 prep was GRID-supply-limited
//    (1173 blocks = 4.6/CU, Occ 28%). Now 32 z-rows/block -> 4688 blocks (18/CU),
//    LDS 8.7 KB, acc = 1 f32x16, afrag = 8 plain bf16 loads (W1 pre-converted).
//  - edge (unchanged, 67us = ~7.7 TB/s L3 gather service ceiling; FETCH-invariant
//    duration across 4MB..225MB proves it's not HBM-bound):
//    out[e] = w2 . relu(U[row[e]] + V[col[e]]) + b2, 16 lanes/edge, ILP=4.

#define HID  128
#define FTE  128    // fallback tile
#define PST  136    // prep LDS row stride (bf16): 128 + 8 pad (row starts 4 banks apart)
#define PTR  32     // prep tile rows

typedef __attribute__((ext_vector_type(8)))  short    bf16x8;   // 8 bf16 = 4 VGPRs
typedef __attribute__((ext_vector_type(16))) float    f32x16;   // 32x32 MFMA accumulator
typedef __attribute__((ext_vector_type(4)))  unsigned uint4v;   // 16 B

__device__ __forceinline__ float bf2f(unsigned short u) {
    return __uint_as_float(((unsigned)u) << 16);
}
__device__ __forceinline__ unsigned pk2(float x, float y) {
    __hip_bfloat162 t = __float22bfloat162_rn(make_float2(x, y));  // packed RNE cvt
    return *reinterpret_cast<unsigned*>(&t);
}
__device__ __forceinline__ bf16x8 pack8(float4 a, float4 b) {
    uint4v r;
    r.x = pk2(a.x, a.y); r.y = pk2(a.z, a.w);
    r.z = pk2(b.x, b.y); r.w = pk2(b.z, b.w);
    return *reinterpret_cast<bf16x8*>(&r);
}

// ---------------- Phase 0: W1 fp32 -> bf16 (one-shot, 32768 elems)
__global__ __launch_bounds__(256)
void w1cvt_kernel(const float* __restrict__ w, unsigned short* __restrict__ ow, int n)
{
    const int i = (blockIdx.x * 256 + threadIdx.x) * 8;
    if (i < n) {
        const float4 a = *(const float4*)(w + i);
        const float4 b = *(const float4*)(w + i + 4);
        *(bf16x8*)(ow + i) = pack8(a, b);
    }
}

// ---------------- Phase 1: U = zs@W1s^T + b1, V = zt@W1t^T  (bf16 out, row-major)
// Block = 256 thr (4 waves), 32 z-rows per block -> 4688 blocks (fixes grid-supply
// starvation). All 4 waves share the 32-row LDS tile; wave w owns hidden [32w,32w+32).
__global__ __launch_bounds__(256)
void prep_kernel(const float* __restrict__ zs, const float* __restrict__ zt,
                 const unsigned short* __restrict__ w1b,   // [128,256] bf16
                 const float* __restrict__ b1,
                 unsigned short* __restrict__ U, unsigned short* __restrict__ V,
                 int NS, int NT, int NBU)
{
    __shared__ __align__(16) unsigned short zl[PTR * PST];   // 8.7 KB bf16

    const bool isU = (int)blockIdx.x < NBU;
    const float* z      = isU ? zs : zt;
    unsigned short* O   = isU ? U  : V;
    const int N    = isU ? NS : NT;
    const int s0   = (isU ? blockIdx.x : blockIdx.x - NBU) * PTR;
    const int koff = isU ? 0 : 128;          // W1 column offset (sotu / taxon half)

    const int tid  = threadIdx.x;
    const int wave = tid >> 6;       // hidden group: rows [32*wave, 32*wave+32)
    const int lane = tid & 63;
    const int l31  = lane & 31;
    const int hlf  = lane >> 5;

    // ---- Stage: 32 rows x 16 chunks. f = i*256+tid: 16 consecutive lanes cover one
    // 512 B fp32 row (fully coalesced). 2 iterations, independent loads.
    #pragma unroll
    for (int i = 0; i < 2; ++i) {
        const int f = i * 256 + tid;
        const int r = f >> 4;                   // tile row 0..31
        const int c = f & 15;                   // chunk 0..15
        int s = s0 + r;
        if (s >= N) s = N - 1;                  // clamp (store guarded)
        const float* src = z + (long long)s * HID + c * 8;
        const float4 a = *(const float4*)(src);
        const float4 b = *(const float4*)(src + 4);
        *(bf16x8*)(zl + r * PST + c * 8) = pack8(a, b);
    }

    // ---- A-frags: bf16 direct loads (L2-hot). A[m=l31][k=hlf*8+j], frag ks = k 16ks..+16.
    bf16x8 afrag[8];
    {
        const unsigned short* wrow = w1b + (32 * wave + l31) * 256 + koff + hlf * 8;
        #pragma unroll
        for (int ks = 0; ks < 8; ++ks)
            afrag[ks] = *(const bf16x8*)(wrow + ks * 16);
    }
    __syncthreads();

    // ---- K-loop: 8 MFMAs. B[n=l31][k=hlf*8+j] from LDS row l31.
    // addr/16 = l31*17 + chunk -> distinct mod 32 (17 odd) -> conflict-free b128.
    f32x16 acc = {};
    #pragma unroll
    for (int ks = 0; ks < 8; ++ks) {
        const bf16x8 bfrag = *(const bf16x8*)(zl + l31 * PST + (2 * ks + hlf) * 8);
        acc = __builtin_amdgcn_mfma_f32_32x32x16_bf16(afrag[ks], bfrag, acc, 0, 0, 0);
    }

    // ---- b1 (U only): lane's 16 hidden = 32w + (reg&3) + 8*(reg>>2) + 4*hlf
    float b1v[16];
    #pragma unroll
    for (int g = 0; g < 4; ++g) {
        const int hb = 32 * wave + 8 * g + 4 * hlf;
        if (isU) {
            const float4 bb = *(const float4*)(b1 + hb);
            b1v[4*g+0] = bb.x; b1v[4*g+1] = bb.y; b1v[4*g+2] = bb.z; b1v[4*g+3] = bb.w;
        } else {
            b1v[4*g+0] = b1v[4*g+1] = b1v[4*g+2] = b1v[4*g+3] = 0.0f;
        }
    }

    // ---- Epilogue: C col=l31 (= z row); store 4 bf16-pairs (8 B) per hidden group.
    const int s = s0 + l31;
    if (s < N) {
        #pragma unroll
        for (int g = 0; g < 4; ++g) {
            const int cb = 32 * wave + 8 * g + 4 * hlf;
            uint2 o;
            o.x = pk2(acc[4*g+0] + b1v[4*g+0], acc[4*g+1] + b1v[4*g+1]);
            o.y = pk2(acc[4*g+2] + b1v[4*g+2], acc[4*g+3] + b1v[4*g+3]);
            *(uint2*)(O + (long long)s * HID + cb) = o;
        }
    }
}

// ---------------- Phase 2: out[e] = w2 . relu(U[row[e]] + V[col[e]]) + b2
// 16 lanes/edge-group, 4 edges per group (8 gathers of 16 B in flight per thread).
__global__ __launch_bounds__(256)
void edge_kernel(const unsigned short* __restrict__ U,   // [NS,128] bf16
                 const unsigned short* __restrict__ V,   // [NT,128] bf16
                 const int*   __restrict__ row, const int* __restrict__ col,
                 const float* __restrict__ w2, const float* __restrict__ b2,
                 float* __restrict__ out, int E)
{
    const int tid = threadIdx.x;
    const int g   = tid >> 4;        // group 0..15
    const int c16 = tid & 15;        // channel chunk (8 channels)

    const long long eb = (long long)blockIdx.x * 64 + g * 4;

    int ri[4], ci[4];
    #pragma unroll
    for (int j = 0; j < 4; ++j) {
        long long e = eb + j;
        if (e >= E) e = E - 1;
        ri[j] = row[e]; ci[j] = col[e];
    }
    bf16x8 u[4], v[4];
    #pragma unroll
    for (int j = 0; j < 4; ++j) {
        u[j] = *(const bf16x8*)(U + (long long)ri[j] * HID + c16 * 8);
        v[j] = *(const bf16x8*)(V + (long long)ci[j] * HID + c16 * 8);
    }

    const float4 wa = *(const float4*)(w2 + c16 * 8);
    const float4 wb = *(const float4*)(w2 + c16 * 8 + 4);
    const float w2v[8] = {wa.x, wa.y, wa.z, wa.w, wb.x, wb.y, wb.z, wb.w};

    float p[4] = {0.0f, 0.0f, 0.0f, 0.0f};
    #pragma unroll
    for (int j = 0; j < 4; ++j) {
        #pragma unroll
        for (int k = 0; k < 8; ++k) {
            const float h = fmaxf(bf2f((unsigned short)u[j][k]) +
                                  bf2f((unsigned short)v[j][k]), 0.0f);
            p[j] = fmaf(h, w2v[k], p[j]);
        }
    }
    #pragma unroll
    for (int d = 1; d < 16; d <<= 1) {
        #pragma unroll
        for (int j = 0; j < 4; ++j) p[j] += __shfl_xor(p[j], d, 64);
    }
    if (c16 == 0) {
        const float bb = b2[0];
        if (eb + 3 < E) {
            *(float4*)(out + eb) = make_float4(p[0] + bb, p[1] + bb, p[2] + bb, p[3] + bb);
        } else {
            #pragma unroll
            for (int j = 0; j < 4; ++j)
                if (eb + j < E) out[eb + j] = p[j] + bb;
        }
    }
}

// ---------------- Fallback: round-2 proven fused kernel (only if ws too small)
__global__ __launch_bounds__(256, 2)
void edge_mlp_fused(const float* __restrict__ z_sotu, const float* __restrict__ z_taxon,
                    const int* __restrict__ row, const int* __restrict__ col,
                    const float* __restrict__ w1, const float* __restrict__ b1,
                    const float* __restrict__ w2, const float* __restrict__ b2,
                    float* __restrict__ out, int E)
{
    __shared__ __align__(16) unsigned short zsh[FTE * 256];
    const int tid  = threadIdx.x;
    const int wave = tid >> 6;
    const int lane = tid & 63;
    const int l31  = lane & 31;
    const int hlf  = lane >> 5;
    const long long e0 = (long long)blockIdx.x * FTE;
    {
        const int ch  = lane & 15;
        const int rhl = lane >> 4;
        #pragma unroll
        for (int pass = 0; pass < 16; ++pass) {
            const int rh = pass * 4 + rhl;
            const int r  = 32 * wave + (rh >> 1);
            const int hh = rh & 1;
            long long e = e0 + r;
            if (e >= E) e = E - 1;
            const int idx = hh ? col[e] : row[e];
            const float* src = (hh ? z_taxon : z_sotu) + (long long)idx * HID + ch * 8;
            const float4 a = *(const float4*)(src);
            const float4 b = *(const float4*)(src + 4);
            const int c = hh * 16 + ch;
            const int q = c ^ (r & 31);
            *(bf16x8*)(zsh + r * 256 + q * 8) = pack8(a, b);
        }
    }
    bf16x8 afrag[16];
    {
        const float* wrow = w1 + (32 * wave + l31) * 256 + hlf * 8;
        #pragma unroll
        for (int ks = 0; ks < 16; ++ks) {
            const float4 a = *(const float4*)(wrow + ks * 16);
            const float4 b = *(const float4*)(wrow + ks * 16 + 4);
            afrag[ks] = pack8(a, b);
        }
    }
    __syncthreads();
    f32x16 acc[4] = {};
    #pragma unroll
    for (int ks = 0; ks < 16; ++ks) {
        #pragma unroll
        for (int nt = 0; nt < 4; ++nt) {
            const int el = 32 * nt + l31;
            const int q  = (2 * ks + hlf) ^ l31;
            bf16x8 bfrag = *(const bf16x8*)(zsh + el * 256 + q * 8);
            acc[nt] = __builtin_amdgcn_mfma_f32_32x32x16_bf16(afrag[ks], bfrag, acc[nt], 0, 0, 0);
        }
    }
    __syncthreads();
    float* partial = (float*)zsh;
    float b1v[16], w2v[16];
    #pragma unroll
    for (int g = 0; g < 4; ++g) {
        const int hb = 32 * wave + 8 * g + 4 * hlf;
        const float4 bb = *(const float4*)(b1 + hb);
        const float4 ww = *(const float4*)(w2 + hb);
        b1v[4*g+0] = bb.x; b1v[4*g+1] = bb.y; b1v[4*g+2] = bb.z; b1v[4*g+3] = bb.w;
        w2v[4*g+0] = ww.x; w2v[4*g+1] = ww.y; w2v[4*g+2] = ww.z; w2v[4*g+3] = ww.w;
    }
    #pragma unroll
    for (int nt = 0; nt < 4; ++nt) {
        float p = 0.0f;
        #pragma unroll
        for (int r = 0; r < 16; ++r) {
            const float h = fmaxf(acc[nt][r] + b1v[r], 0.0f);
            p = fmaf(h, w2v[r], p);
        }
        p += __shfl_xor(p, 32, 64);
        if (hlf == 0)
            partial[wave * FTE + 32 * nt + l31] = p;
    }
    __syncthreads();
    if (tid < FTE) {
        const long long e = e0 + tid;
        if (e < E) {
            out[e] = partial[0 * FTE + tid] + partial[1 * FTE + tid]
                   + partial[2 * FTE + tid] + partial[3 * FTE + tid]
                   + b2[0];
        }
    }
}

extern "C" void kernel_launch(void* const* d_in, const int* in_sizes, int n_in,
                              void* d_out, int out_size, void* d_ws, size_t ws_size,
                              hipStream_t stream) {
    const float* z_sotu  = (const float*)d_in[0];
    const float* z_taxon = (const float*)d_in[1];
    const int*   row     = (const int*)d_in[2];
    const int*   col     = (const int*)d_in[3];
    const float* w1      = (const float*)d_in[4];
    const float* b1      = (const float*)d_in[5];
    const float* w2      = (const float*)d_in[6];
    const float* b2      = (const float*)d_in[7];
    float*       out     = (float*)d_out;

    const int NS = in_sizes[0] / HID;   // 100000
    const int NT = in_sizes[1] / HID;   //  50000
    const int EW = in_sizes[4];         //  32768
    const int E  = in_sizes[2];
    const size_t need = ((size_t)NS + NT) * HID * 2 + (size_t)EW * 2;

    if (ws_size >= need) {
        unsigned short* U   = (unsigned short*)d_ws;
        unsigned short* Vv  = U + (size_t)NS * HID;
        unsigned short* w1b = Vv + (size_t)NT * HID;
        hipLaunchKernelGGL(w1cvt_kernel, dim3((EW / 8 + 255) / 256), dim3(256), 0, stream,
                           w1, w1b, EW);
        const int NBU = (NS + PTR - 1) / PTR;
        const int NBV = (NT + PTR - 1) / PTR;
        hipLaunchKernelGGL(prep_kernel, dim3(NBU + NBV), dim3(256), 0, stream,
                           z_sotu, z_taxon, w1b, b1, U, Vv, NS, NT, NBU);
        const int nblocks = (E + 63) / 64;
        hipLaunchKernelGGL(edge_kernel, dim3(nblocks), dim3(256), 0, stream,
                           U, Vv, row, col, w2, b2, out, E);
    } else {
        const int nblocks = (E + FTE - 1) / FTE;
        hipLaunchKernelGGL(edge_mlp_fused, dim3(nblocks), dim3(256), 0, stream,
                           z_sotu, z_taxon, row, col, w1, b1, w2, b2, out, E);
    }
}

// Round 9
// 199.107 us; speedup vs baseline: 1.0448x; 1.0448x over previous
//
#include <hip/hip_runtime.h>
#include <hip/hip_bf16.h>

// EdgeDecoder: out[e] = w2 . relu(W1 @ concat(z_sotu[row[e]], z_taxon[col[e]]) + b1) + b2
// E=1e6, H=128, K=2H=256. fp32 inputs, int32 indices, fp32 output.
//
// Round 9 (U/V decomposition; budget: ~80us fixed harness overhead + prep + edge):
//  - prep v4: U = zs@W1s^T + b1, V = zt@W1t^T. R8 showed prep is NOT grid-supply
//    limited (32-row blocks changed nothing): each block was one un-pipelined HBM
//    round trip (load -> barrier -> 8 MFMA -> exit). Now PERSISTENT blocks:
//    grid 1536 (blocks [0,1024) own U-tiles, [1024,1536) own V-tiles -> one afrag
//    set each), each strides over ~3 tiles of 32 rows with DOUBLE-BUFFERED LDS
//    (2 x 8.7 KB): stage tile t+step while computing tile t; 1 barrier/tile.
//  - edge (unchanged control, 65 us = gather service ceiling; FETCH-invariant):
//    out[e] = w2 . relu(U[row[e]] + V[col[e]]) + b2, 16 lanes/edge, ILP=4.

#define HID  128
#define FTE  128    // fallback tile
#define PST  136    // prep LDS row stride (bf16): 128 + 8 pad
#define PTR  32     // prep tile rows
#define GU   1024   // prep blocks owning U (sotu) tiles
#define GT   512    // prep blocks owning V (taxon) tiles

typedef __attribute__((ext_vector_type(8)))  short    bf16x8;   // 8 bf16 = 4 VGPRs
typedef __attribute__((ext_vector_type(16))) float    f32x16;   // 32x32 MFMA accumulator
typedef __attribute__((ext_vector_type(4)))  unsigned uint4v;   // 16 B

__device__ __forceinline__ float bf2f(unsigned short u) {
    return __uint_as_float(((unsigned)u) << 16);
}
__device__ __forceinline__ unsigned pk2(float x, float y) {
    __hip_bfloat162 t = __float22bfloat162_rn(make_float2(x, y));  // packed RNE cvt
    return *reinterpret_cast<unsigned*>(&t);
}
__device__ __forceinline__ bf16x8 pack8(float4 a, float4 b) {
    uint4v r;
    r.x = pk2(a.x, a.y); r.y = pk2(a.z, a.w);
    r.z = pk2(b.x, b.y); r.w = pk2(b.z, b.w);
    return *reinterpret_cast<bf16x8*>(&r);
}

// ---------------- Phase 1: U = zs@W1s^T + b1, V = zt@W1t^T  (bf16 out, row-major)
// Persistent blocks, double-buffered 32-row tiles.
__global__ __launch_bounds__(256)
void prep_kernel(const float* __restrict__ zs, const float* __restrict__ zt,
                 const float* __restrict__ w1, const float* __restrict__ b1,
                 unsigned short* __restrict__ U, unsigned short* __restrict__ V,
                 int NS, int NT)
{
    __shared__ __align__(16) unsigned short zl[2][PTR * PST];   // 2 x 8.7 KB

    const bool isU = (int)blockIdx.x < GU;
    const float* z      = isU ? zs : zt;
    unsigned short* O   = isU ? U  : V;
    const int N    = isU ? NS : NT;
    const int nT   = (N + PTR - 1) / PTR;            // tiles in this region
    const int t0   = isU ? blockIdx.x : blockIdx.x - GU;
    const int step = isU ? GU : GT;
    const int koff = isU ? 0 : 128;                  // W1 column offset

    const int tid  = threadIdx.x;
    const int wave = tid >> 6;       // hidden group: rows [32*wave, 32*wave+32)
    const int lane = tid & 63;
    const int l31  = lane & 31;
    const int hlf  = lane >> 5;

    if (t0 >= nT) return;

    // Stage one 32-row tile into buf: 16 consecutive lanes cover one 512 B fp32 row.
    auto stage = [&](int t, unsigned short* buf) {
        #pragma unroll
        for (int i = 0; i < 2; ++i) {
            const int f = i * 256 + tid;
            const int r = f >> 4;                   // tile row 0..31
            const int c = f & 15;                   // chunk 0..15
            int s = t * PTR + r;
            if (s >= N) s = N - 1;                  // clamp (store guarded)
            const float* src = z + (long long)s * HID + c * 8;
            const float4 a = *(const float4*)(src);
            const float4 b = *(const float4*)(src + 4);
            *(bf16x8*)(buf + r * PST + c * 8) = pack8(a, b);
        }
    };

    // First tile into buf0; afrag/b1 loads overlap the staging latency.
    stage(t0, zl[0]);

    // A-frags: fp32 W1 -> bf16 once per block. A[m=l31][k=hlf*8+j], frag ks = k 16ks..+16.
    bf16x8 afrag[8];
    {
        const float* wrow = w1 + (32 * wave + l31) * 256 + koff + hlf * 8;
        #pragma unroll
        for (int ks = 0; ks < 8; ++ks) {
            const float4 a = *(const float4*)(wrow + ks * 16);
            const float4 b = *(const float4*)(wrow + ks * 16 + 4);
            afrag[ks] = pack8(a, b);
        }
    }
    // b1 (U only): lane's 16 hidden = 32w + (reg&3) + 8*(reg>>2) + 4*hlf
    float b1v[16];
    #pragma unroll
    for (int g = 0; g < 4; ++g) {
        const int hb = 32 * wave + 8 * g + 4 * hlf;
        if (isU) {
            const float4 bb = *(const float4*)(b1 + hb);
            b1v[4*g+0] = bb.x; b1v[4*g+1] = bb.y; b1v[4*g+2] = bb.z; b1v[4*g+3] = bb.w;
        } else {
            b1v[4*g+0] = b1v[4*g+1] = b1v[4*g+2] = b1v[4*g+3] = 0.0f;
        }
    }
    __syncthreads();

    int p = 0;
    for (int t = t0; t < nT; ) {
        const int tn = t + step;
        if (tn < nT) stage(tn, zl[p ^ 1]);          // prefetch next tile (other buffer)

        // Compute tile t: 8 MFMAs; B[n=l31][k=hlf*8+j] from LDS row l31.
        f32x16 acc = {};
        #pragma unroll
        for (int ks = 0; ks < 8; ++ks) {
            const bf16x8 bfrag = *(const bf16x8*)(zl[p] + l31 * PST + (2 * ks + hlf) * 8);
            acc = __builtin_amdgcn_mfma_f32_32x32x16_bf16(afrag[ks], bfrag, acc, 0, 0, 0);
        }
        // Epilogue: C col=l31 (= z row); 4 x 8 B stores.
        const int s = t * PTR + l31;
        if (s < N) {
            #pragma unroll
            for (int g = 0; g < 4; ++g) {
                const int cb = 32 * wave + 8 * g + 4 * hlf;
                uint2 o;
                o.x = pk2(acc[4*g+0] + b1v[4*g+0], acc[4*g+1] + b1v[4*g+1]);
                o.y = pk2(acc[4*g+2] + b1v[4*g+2], acc[4*g+3] + b1v[4*g+3]);
                *(uint2*)(O + (long long)s * HID + cb) = o;
            }
        }
        __syncthreads();      // reads of zl[p] done; writes to zl[p^1] complete
        p ^= 1;
        t = tn;
    }
}

// ---------------- Phase 2: out[e] = w2 . relu(U[row[e]] + V[col[e]]) + b2
// 16 lanes/edge-group, 4 edges per group (8 gathers of 16 B in flight per thread).
__global__ __launch_bounds__(256)
void edge_kernel(const unsigned short* __restrict__ U,   // [NS,128] bf16
                 const unsigned short* __restrict__ V,   // [NT,128] bf16
                 const int*   __restrict__ row, const int* __restrict__ col,
                 const float* __restrict__ w2, const float* __restrict__ b2,
                 float* __restrict__ out, int E)
{
    const int tid = threadIdx.x;
    const int g   = tid >> 4;        // group 0..15
    const int c16 = tid & 15;        // channel chunk (8 channels)

    const long long eb = (long long)blockIdx.x * 64 + g * 4;

    int ri[4], ci[4];
    #pragma unroll
    for (int j = 0; j < 4; ++j) {
        long long e = eb + j;
        if (e >= E) e = E - 1;
        ri[j] = row[e]; ci[j] = col[e];
    }
    bf16x8 u[4], v[4];
    #pragma unroll
    for (int j = 0; j < 4; ++j) {
        u[j] = *(const bf16x8*)(U + (long long)ri[j] * HID + c16 * 8);
        v[j] = *(const bf16x8*)(V + (long long)ci[j] * HID + c16 * 8);
    }

    const float4 wa = *(const float4*)(w2 + c16 * 8);
    const float4 wb = *(const float4*)(w2 + c16 * 8 + 4);
    const float w2v[8] = {wa.x, wa.y, wa.z, wa.w, wb.x, wb.y, wb.z, wb.w};

    float p[4] = {0.0f, 0.0f, 0.0f, 0.0f};
    #pragma unroll
    for (int j = 0; j < 4; ++j) {
        #pragma unroll
        for (int k = 0; k < 8; ++k) {
            const float h = fmaxf(bf2f((unsigned short)u[j][k]) +
                                  bf2f((unsigned short)v[j][k]), 0.0f);
            p[j] = fmaf(h, w2v[k], p[j]);
        }
    }
    #pragma unroll
    for (int d = 1; d < 16; d <<= 1) {
        #pragma unroll
        for (int j = 0; j < 4; ++j) p[j] += __shfl_xor(p[j], d, 64);
    }
    if (c16 == 0) {
        const float bb = b2[0];
        if (eb + 3 < E) {
            *(float4*)(out + eb) = make_float4(p[0] + bb, p[1] + bb, p[2] + bb, p[3] + bb);
        } else {
            #pragma unroll
            for (int j = 0; j < 4; ++j)
                if (eb + j < E) out[eb + j] = p[j] + bb;
        }
    }
}

// ---------------- Fallback: round-2 proven fused kernel (only if ws too small)
__global__ __launch_bounds__(256, 2)
void edge_mlp_fused(const float* __restrict__ z_sotu, const float* __restrict__ z_taxon,
                    const int* __restrict__ row, const int* __restrict__ col,
                    const float* __restrict__ w1, const float* __restrict__ b1,
                    const float* __restrict__ w2, const float* __restrict__ b2,
                    float* __restrict__ out, int E)
{
    __shared__ __align__(16) unsigned short zsh[FTE * 256];
    const int tid  = threadIdx.x;
    const int wave = tid >> 6;
    const int lane = tid & 63;
    const int l31  = lane & 31;
    const int hlf  = lane >> 5;
    const long long e0 = (long long)blockIdx.x * FTE;
    {
        const int ch  = lane & 15;
        const int rhl = lane >> 4;
        #pragma unroll
        for (int pass = 0; pass < 16; ++pass) {
            const int rh = pass * 4 + rhl;
            const int r  = 32 * wave + (rh >> 1);
            const int hh = rh & 1;
            long long e = e0 + r;
            if (e >= E) e = E - 1;
            const int idx = hh ? col[e] : row[e];
            const float* src = (hh ? z_taxon : z_sotu) + (long long)idx * HID + ch * 8;
            const float4 a = *(const float4*)(src);
            const float4 b = *(const float4*)(src + 4);
            const int c = hh * 16 + ch;
            const int q = c ^ (r & 31);
            *(bf16x8*)(zsh + r * 256 + q * 8) = pack8(a, b);
        }
    }
    bf16x8 afrag[16];
    {
        const float* wrow = w1 + (32 * wave + l31) * 256 + hlf * 8;
        #pragma unroll
        for (int ks = 0; ks < 16; ++ks) {
            const float4 a = *(const float4*)(wrow + ks * 16);
            const float4 b = *(const float4*)(wrow + ks * 16 + 4);
            afrag[ks] = pack8(a, b);
        }
    }
    __syncthreads();
    f32x16 acc[4] = {};
    #pragma unroll
    for (int ks = 0; ks < 16; ++ks) {
        #pragma unroll
        for (int nt = 0; nt < 4; ++nt) {
            const int el = 32 * nt + l31;
            const int q  = (2 * ks + hlf) ^ l31;
            bf16x8 bfrag = *(const bf16x8*)(zsh + el * 256 + q * 8);
            acc[nt] = __builtin_amdgcn_mfma_f32_32x32x16_bf16(afrag[ks], bfrag, acc[nt], 0, 0, 0);
        }
    }
    __syncthreads();
    float* partial = (float*)zsh;
    float b1v[16], w2v[16];
    #pragma unroll
    for (int g = 0; g < 4; ++g) {
        const int hb = 32 * wave + 8 * g + 4 * hlf;
        const float4 bb = *(const float4*)(b1 + hb);
        const float4 ww = *(const float4*)(w2 + hb);
        b1v[4*g+0] = bb.x; b1v[4*g+1] = bb.y; b1v[4*g+2] = bb.z; b1v[4*g+3] = bb.w;
        w2v[4*g+0] = ww.x; w2v[4*g+1] = ww.y; w2v[4*g+2] = ww.z; w2v[4*g+3] = ww.w;
    }
    #pragma unroll
    for (int nt = 0; nt < 4; ++nt) {
        float p = 0.0f;
        #pragma unroll
        for (int r = 0; r < 16; ++r) {
            const float h = fmaxf(acc[nt][r] + b1v[r], 0.0f);
            p = fmaf(h, w2v[r], p);
        }
        p += __shfl_xor(p, 32, 64);
        if (hlf == 0)
            partial[wave * FTE + 32 * nt + l31] = p;
    }
    __syncthreads();
    if (tid < FTE) {
        const long long e = e0 + tid;
        if (e < E) {
            out[e] = partial[0 * FTE + tid] + partial[1 * FTE + tid]
                   + partial[2 * FTE + tid] + partial[3 * FTE + tid]
                   + b2[0];
        }
    }
}

extern "C" void kernel_launch(void* const* d_in, const int* in_sizes, int n_in,
                              void* d_out, int out_size, void* d_ws, size_t ws_size,
                              hipStream_t stream) {
    const float* z_sotu  = (const float*)d_in[0];
    const float* z_taxon = (const float*)d_in[1];
    const int*   row     = (const int*)d_in[2];
    const int*   col     = (const int*)d_in[3];
    const float* w1      = (const float*)d_in[4];
    const float* b1      = (const float*)d_in[5];
    const float* w2      = (const float*)d_in[6];
    const float* b2      = (const float*)d_in[7];
    float*       out     = (float*)d_out;

    const int NS = in_sizes[0] / HID;   // 100000
    const int NT = in_sizes[1] / HID;   //  50000
    const int E  = in_sizes[2];
    const size_t need = ((size_t)NS + NT) * HID * 2;   // 38.4 MB bf16 U+V

    if (ws_size >= need) {
        unsigned short* U  = (unsigned short*)d_ws;
        unsigned short* Vv = U + (size_t)NS * HID;
        hipLaunchKernelGGL(prep_kernel, dim3(GU + GT), dim3(256), 0, stream,
                           z_sotu, z_taxon, w1, b1, U, Vv, NS, NT);
        const int nblocks = (E + 63) / 64;
        hipLaunchKernelGGL(edge_kernel, dim3(nblocks), dim3(256), 0, stream,
                           U, Vv, row, col, w2, b2, out, E);
    } else {
        const int nblocks = (E + FTE - 1) / FTE;
        hipLaunchKernelGGL(edge_mlp_fused, dim3(nblocks), dim3(256), 0, stream,
                           z_sotu, z_taxon, row, col, w1, b1, w2, b2, out, E);
    }
}